// Round 2
// baseline (5333.556 us; speedup 1.0000x reference)
//
#include <hip/hip_runtime.h>

// ---------------- problem constants ----------------
#define VV 50000
#define EE 512
#define HH 256
#define BB 32
#define SS 1024
#define G4 1024   // 4*H

typedef __attribute__((ext_vector_type(8))) short short8;
typedef __attribute__((ext_vector_type(4))) float float4v;
typedef __attribute__((ext_vector_type(2))) float float2v;
typedef __attribute__((ext_vector_type(4))) unsigned short ushort4v;

#define MFMA(a, b, c) __builtin_amdgcn_mfma_f32_16x16x32_bf16(a, b, c, 0, 0, 0)

__device__ __forceinline__ float b2f(unsigned short u) {
  union { unsigned int i; float f; } v; v.i = ((unsigned int)u) << 16; return v.f;
}
__device__ __forceinline__ unsigned short f2b(float f) {
  union { float f; unsigned int i; } v; v.f = f;
  unsigned int u = v.i;
  return (unsigned short)((u + 0x7fffu + ((u >> 16) & 1u)) >> 16);
}
// pack 8 consecutive fp32 (16B-aligned) -> short8 of bf16
__device__ __forceinline__ short8 pack8(const float* p) {
  float4v x0 = *(const float4v*)p;
  float4v x1 = *(const float4v*)(p + 4);
  short8 r;
  r[0] = (short)f2b(x0[0]); r[1] = (short)f2b(x0[1]);
  r[2] = (short)f2b(x0[2]); r[3] = (short)f2b(x0[3]);
  r[4] = (short)f2b(x1[0]); r[5] = (short)f2b(x1[1]);
  r[6] = (short)f2b(x1[2]); r[7] = (short)f2b(x1[3]);
  return r;
}
__device__ __forceinline__ float sigm(float x) {
  return __builtin_amdgcn_rcpf(1.0f + __expf(-x));
}
__device__ __forceinline__ float tanh_f(float x) {
  return 1.0f - 2.0f * __builtin_amdgcn_rcpf(__expf(2.0f * x) + 1.0f);
}

// ---------------- kernel 1: fmask scan -> order/counts ----------------
__global__ __launch_bounds__(256) void k_scan(const int* __restrict__ fmask,
                                              int* __restrict__ order,
                                              int* __restrict__ counts) {
  __shared__ int sh[256];
  const int b = blockIdx.x;
  const int tid = threadIdx.x;
  int m0[4];
  const int base = b * SS + tid * 4;
#pragma unroll
  for (int j = 0; j < 4; ++j) m0[j] = fmask[base + j];
  const int s = m0[0] + m0[1] + m0[2] + m0[3];
  sh[tid] = s;
  __syncthreads();
  for (int off = 1; off < 256; off <<= 1) {
    int v = 0;
    if (tid >= off) v = sh[tid - off];
    __syncthreads();
    sh[tid] += v;
    __syncthreads();
  }
  const int incl = sh[tid];
  int pos = incl - s;
#pragma unroll
  for (int j = 0; j < 4; ++j) {
    if (m0[j]) order[b * SS + pos++] = tid * 4 + j;
  }
  if (tid == 255) counts[b] = incl;
}

// ---------------- kernel 2: embedding-gather + input GEMM ----------------
// xg[d][t][b][gate] (bf16), computed as C^T via swapped MFMA operands.
#define BM 128
#define BN 128
#define BK 32
#define LSTR 56

__global__ __launch_bounds__(256, 2) void k_gemm(
    const int* __restrict__ inputs, const int* __restrict__ seqlen,
    const float* __restrict__ emb,
    const float* __restrict__ Wih_f, const float* __restrict__ Wih_b,
    const float* __restrict__ bih_f, const float* __restrict__ bih_b,
    const float* __restrict__ bhh_f, const float* __restrict__ bhh_b,
    unsigned short* __restrict__ xg) {
  __shared__ short As[BM * LSTR];
  __shared__ short Bs[BN * LSTR];
  __shared__ int tokL[BM];

  const int d = blockIdx.y;
  const int mt = blockIdx.x >> 3, nt = blockIdx.x & 7;
  const int Mbase = mt * BM, Nbase = nt * BN;
  const int tid = threadIdx.x;
  const float* Wih = d ? Wih_b : Wih_f;

  if (tid < BM) {
    const int m = Mbase + tid;
    const int t = m >> 5, b = m & 31;
    int tok;
    if (d == 0) {
      tok = inputs[b * SS + t];
    } else {
      const int L = seqlen[b];
      tok = (t < L) ? inputs[b * SS + (L - 1 - t)] : 0;
    }
    tokL[tid] = tok;
  }
  __syncthreads();

  const int wave = tid >> 6, lane = tid & 63, ln = lane & 15, q = lane >> 4;
  const int wm = wave & 1, wn = wave >> 1;

  float4v acc[4][4];   // [ni (gate tile)][mi (txb tile)]
#pragma unroll
  for (int ni = 0; ni < 4; ++ni)
#pragma unroll
    for (int mi = 0; mi < 4; ++mi) acc[ni][mi] = (float4v){0.f, 0.f, 0.f, 0.f};

  for (int kb = 0; kb < (EE / BK); ++kb) {
    const int k0 = kb * BK;
    if (kb) __syncthreads();
#pragma unroll
    for (int i = 0; i < 2; ++i) {
      const int c = tid + i * 256;
      const int row = c >> 2, sub = c & 3;
      const short8 av = pack8(emb + (size_t)tokL[row] * EE + k0 + sub * 8);
      *(short8*)(As + row * LSTR + sub * 8) = av;
      const short8 bv = pack8(Wih + (size_t)(Nbase + row) * EE + k0 + sub * 8);
      *(short8*)(Bs + row * LSTR + sub * 8) = bv;
    }
    __syncthreads();
    short8 af[4], bfr[4];
#pragma unroll
    for (int mi = 0; mi < 4; ++mi)
      af[mi] = *(const short8*)(As + (wm * 64 + mi * 16 + ln) * LSTR + q * 8);
#pragma unroll
    for (int ni = 0; ni < 4; ++ni)
      bfr[ni] = *(const short8*)(Bs + (wn * 64 + ni * 16 + ln) * LSTR + q * 8);
#pragma unroll
    for (int ni = 0; ni < 4; ++ni)
#pragma unroll
      for (int mi = 0; mi < 4; ++mi)
        acc[ni][mi] = MFMA(bfr[ni], af[mi], acc[ni][mi]);   // swapped operands
  }

  const float* bih = d ? bih_b : bih_f;
  const float* bhh = d ? bhh_b : bhh_f;
  float biasv[4][4];
#pragma unroll
  for (int ni = 0; ni < 4; ++ni)
#pragma unroll
    for (int r = 0; r < 4; ++r) {
      const int col = Nbase + wn * 64 + ni * 16 + q * 4 + r;
      biasv[ni][r] = bih[col] + bhh[col];
    }
#pragma unroll
  for (int ni = 0; ni < 4; ++ni) {
    const int gate0 = Nbase + wn * 64 + ni * 16 + q * 4;
#pragma unroll
    for (int mi = 0; mi < 4; ++mi) {
      const int m = Mbase + wm * 64 + mi * 16 + ln;
      const int t = m >> 5, b0 = m & 31;
      ushort4v pk;
#pragma unroll
      for (int r = 0; r < 4; ++r) pk[r] = f2b(acc[ni][mi][r] + biasv[ni][r]);
      *(ushort4v*)(xg + (((size_t)d * SS + t) * BB + b0) * G4 + gate0) = pk;
    }
  }
}

// ---------------- kernel 3: recurrence (sentinel dataflow sync via MALL) ----------------
// vs round-0 (3250us): the counter machinery (store -> vmcnt(0) drain ->
// atomicAdd -> wave0 counter-poll -> barrier -> separate h load) is replaced
// by self-flagging data: hbuf is pre-poisoned 0x7f7f (bf16 3.4e38 --
// unreachable, |h|<=1; 8B stores don't tear), producers publish h with one
// agent-scope 8B store, consumers spin directly on the 16 data qwords until
// none equals the sentinel. The poll IS the load: no barriers, no atomics,
// no drain in the steady loop; the 4 waves run fully async (drift bounded
// by the data DAG). All traffic uses the proven round-0 substrate
// (agent-scope __hip_atomic_* -> MALL coherence point) -- correct under any
// block->XCD placement. t=0 skips the h-GEMM entirely (h_0 = 0), so hbuf
// slot 0 is never read.
#define SENTQ 0x7f7f7f7f7f7f7f7full

__global__ __launch_bounds__(256, 1) void k_recur(
    const float* __restrict__ Whh_f, const float* __restrict__ Whh_b,
    const unsigned short* __restrict__ xg, unsigned short* __restrict__ hbuf) {
  const int beta = blockIdx.x;
  const int xcd = beta & 7, slot = beta >> 3;   // blockIdx%8 ~ XCD (perf heuristic only)
  if (xcd >= 2) return;
  const int d = xcd, k = slot;
  const float* Whh = d ? Whh_b : Whh_f;
  const int tid = threadIdx.x;
  const int lane = tid & 63, ln = lane & 15, q = lane >> 4;
  const int wave = tid >> 6;
  const int g = wave & 1, nw = wave >> 1;
  const int chain = nw * 16 + ln;               // this lane's batch chain (C col)
  const int ubase = k * 32 + g * 16 + q * 4;    // first of this lane's 4 units (C rows)

  // loop-invariant weight fragments: A[m][kk], m=ln, kk=q*8+j
  short8 w[4][8];
#pragma unroll
  for (int G = 0; G < 4; ++G) {
    const int grow = G * 256 + k * 32 + g * 16 + ln;
#pragma unroll
    for (int kt = 0; kt < 8; ++kt)
      w[G][kt] = pack8(Whh + (size_t)grow * HH + kt * 32 + q * 8);
  }

  float c4[4] = {0.f, 0.f, 0.f, 0.f};
  unsigned short* hb = hbuf + (size_t)d * 1025 * BB * HH;
  const unsigned short* xgd = xg + (size_t)d * SS * BB * G4;

  // xg for t=0 (transposed layout: 4 gates x 4 units contiguous per lane)
  ushort4v xc4[4], xn4[4];
#pragma unroll
  for (int G = 0; G < 4; ++G)
    xc4[G] = *(const ushort4v*)(xgd + ((size_t)0 * BB + chain) * G4 + G * 256 + ubase);

  for (int t = 0; t < SS; ++t) {
    unsigned long long qv[16];
    if (t > 0) {
      // sentinel-poll h_t row for this chain (poll == load; MALL-coherent)
      const unsigned long long* hq =
          (const unsigned long long*)(hb + ((size_t)t * BB + chain) * HH) + q * 2;
      bool bad = true;
      while (bad) {
#pragma unroll
        for (int i = 0; i < 16; ++i)
          qv[i] = __hip_atomic_load(hq + (i >> 1) * 8 + (i & 1),
                                    __ATOMIC_RELAXED, __HIP_MEMORY_SCOPE_AGENT);
        bad = false;
#pragma unroll
        for (int i = 0; i < 16; ++i) bad |= (qv[i] == SENTQ);
      }
    }

    // prefetch next step's xg after the poll: consumed at the end-of-loop
    // copy, so the MFMA+gate phase (~700cy) covers its latency.
    if (t + 1 < SS) {
#pragma unroll
      for (int G = 0; G < 4; ++G)
        xn4[G] = *(const ushort4v*)(xgd + ((size_t)(t + 1) * BB + chain) * G4 +
                                    G * 256 + ubase);
    }

    float4v acc[4];
#pragma unroll
    for (int G = 0; G < 4; ++G) acc[G] = (float4v){0.f, 0.f, 0.f, 0.f};
    if (t > 0) {
#pragma unroll
      for (int kt = 0; kt < 8; ++kt) {
        union { unsigned long long u[2]; short8 s; } hh;
        hh.u[0] = qv[kt * 2]; hh.u[1] = qv[kt * 2 + 1];
#pragma unroll
        for (int G = 0; G < 4; ++G) acc[G] = MFMA(w[G][kt], hh.s, acc[G]);
      }
    }

    unsigned long long pv = 0ull;
#pragma unroll
    for (int r = 0; r < 4; ++r) {
      const float gi = acc[0][r] + b2f(xc4[0][r]);
      const float gf = acc[1][r] + b2f(xc4[1][r]);
      const float gg = acc[2][r] + b2f(xc4[2][r]);
      const float go = acc[3][r] + b2f(xc4[3][r]);
      const float cn = sigm(gf) * c4[r] + sigm(gi) * tanh_f(gg);
      c4[r] = cn;
      const float h = sigm(go) * tanh_f(cn);
      pv |= ((unsigned long long)f2b(h)) << (16 * r);
    }
    // publish h_{t+1}: one agent-scope 8B store; the data itself is the flag.
    __hip_atomic_store(
        (unsigned long long*)(hb + ((size_t)(t + 1) * BB + chain) * HH + ubase),
        pv, __ATOMIC_RELAXED, __HIP_MEMORY_SCOPE_AGENT);

#pragma unroll
    for (int G = 0; G < 4; ++G) xc4[G] = xn4[G];
  }
}

// ---------------- kernel 4: masked compaction gather -> out (fp32) ----------------
__global__ __launch_bounds__(256) void k_gather(
    const unsigned short* __restrict__ hbuf, const int* __restrict__ order,
    const int* __restrict__ counts, float* __restrict__ out) {
  const int bj = blockIdx.x;            // (b, j)
  const int b = bj >> 10, j = bj & 1023;
  const int tid = threadIdx.x;
  const int cnt = counts[b];
  float2v val = (float2v){0.f, 0.f};
  if (j < cnt) {
    const int half = tid >> 7;          // 0: forward, 1: backward
    const int e2 = (tid & 127) * 2;
    const int tsel = half ? order[b * SS + (cnt - 1 - j)] : order[b * SS + j];
    const unsigned short* src =
        hbuf + (((size_t)half * 1025 + (tsel + 1)) * BB + b) * HH + e2;
    const unsigned int u = *(const unsigned int*)src;
    val[0] = b2f((unsigned short)u);
    val[1] = b2f((unsigned short)(u >> 16));
  }
  *(float2v*)(out + (size_t)bj * 512 + tid * 2) = val;
}

// ---------------- host ----------------
extern "C" void kernel_launch(void* const* d_in, const int* in_sizes, int n_in,
                              void* d_out, int out_size, void* d_ws, size_t ws_size,
                              hipStream_t stream) {
  (void)in_sizes; (void)n_in; (void)out_size; (void)ws_size;
  const int* inputs = (const int*)d_in[0];
  const int* seqlen = (const int*)d_in[1];
  const int* fmask  = (const int*)d_in[2];
  const float* emb  = (const float*)d_in[5];
  const float* fWih = (const float*)d_in[6];
  const float* fWhh = (const float*)d_in[7];
  const float* fbih = (const float*)d_in[8];
  const float* fbhh = (const float*)d_in[9];
  const float* bWih = (const float*)d_in[10];
  const float* bWhh = (const float*)d_in[11];
  const float* bbih = (const float*)d_in[12];
  const float* bbhh = (const float*)d_in[13];
  float* out = (float*)d_out;

  char* ws = (char*)d_ws;
  int* counts = (int*)(ws + 12800);             // 32 ints
  int* order  = (int*)(ws + 16384);             // 32*1024 ints
  const size_t o_hbuf = (size_t)1 << 18;
  unsigned short* hbuf = (unsigned short*)(ws + o_hbuf);          // 2*1025*32*256 bf16
  const size_t hbuf_bytes = (size_t)2 * 1025 * BB * HH * 2;       // 33,587,200
  const size_t o_xg = o_hbuf + hbuf_bytes;
  unsigned short* xg = (unsigned short*)(ws + o_xg);              // 2*1024*32*1024 bf16

  // poison hbuf with the sentinel pattern (bf16 0x7f7f = 3.4e38, a value the
  // recurrence can never produce); slot 0 is never read (t=0 skips the GEMM).
  hipMemsetAsync(hbuf, 0x7f, hbuf_bytes, stream);

  k_scan<<<32, 256, 0, stream>>>(fmask, order, counts);
  k_gemm<<<dim3(2048, 2), 256, 0, stream>>>(inputs, seqlen, emb, fWih, bWih,
                                            fbih, bbih, fbhh, bbhh, xg);
  k_recur<<<64, 256, 0, stream>>>(fWhh, bWhh, xg, hbuf);
  k_gather<<<BB * SS, 256, 0, stream>>>(hbuf, order, counts, out);
}

// Round 3
// 3689.738 us; speedup vs baseline: 1.4455x; 1.4455x over previous
//
#include <hip/hip_runtime.h>

// ---------------- problem constants ----------------
#define VV 50000
#define EE 512
#define HH 256
#define BB 32
#define SS 1024
#define G4 1024   // 4*H

typedef __attribute__((ext_vector_type(8))) short short8;
typedef __attribute__((ext_vector_type(4))) float float4v;
typedef __attribute__((ext_vector_type(2))) float float2v;
typedef __attribute__((ext_vector_type(4))) unsigned short ushort4v;

#define MFMA(a, b, c) __builtin_amdgcn_mfma_f32_16x16x32_bf16(a, b, c, 0, 0, 0)

__device__ __forceinline__ float b2f(unsigned short u) {
  union { unsigned int i; float f; } v; v.i = ((unsigned int)u) << 16; return v.f;
}
__device__ __forceinline__ unsigned short f2b(float f) {
  union { float f; unsigned int i; } v; v.f = f;
  unsigned int u = v.i;
  return (unsigned short)((u + 0x7fffu + ((u >> 16) & 1u)) >> 16);
}
// pack 8 consecutive fp32 (16B-aligned) -> short8 of bf16
__device__ __forceinline__ short8 pack8(const float* p) {
  float4v x0 = *(const float4v*)p;
  float4v x1 = *(const float4v*)(p + 4);
  short8 r;
  r[0] = (short)f2b(x0[0]); r[1] = (short)f2b(x0[1]);
  r[2] = (short)f2b(x0[2]); r[3] = (short)f2b(x0[3]);
  r[4] = (short)f2b(x1[0]); r[5] = (short)f2b(x1[1]);
  r[6] = (short)f2b(x1[2]); r[7] = (short)f2b(x1[3]);
  return r;
}
__device__ __forceinline__ float sigm(float x) {
  return __builtin_amdgcn_rcpf(1.0f + __expf(-x));
}
__device__ __forceinline__ float tanh_f(float x) {
  return 1.0f - 2.0f * __builtin_amdgcn_rcpf(__expf(2.0f * x) + 1.0f);
}

// ---------------- kernel 1: fmask scan -> order/counts ----------------
__global__ __launch_bounds__(256) void k_scan(const int* __restrict__ fmask,
                                              int* __restrict__ order,
                                              int* __restrict__ counts) {
  __shared__ int sh[256];
  const int b = blockIdx.x;
  const int tid = threadIdx.x;
  int m0[4];
  const int base = b * SS + tid * 4;
#pragma unroll
  for (int j = 0; j < 4; ++j) m0[j] = fmask[base + j];
  const int s = m0[0] + m0[1] + m0[2] + m0[3];
  sh[tid] = s;
  __syncthreads();
  for (int off = 1; off < 256; off <<= 1) {
    int v = 0;
    if (tid >= off) v = sh[tid - off];
    __syncthreads();
    sh[tid] += v;
    __syncthreads();
  }
  const int incl = sh[tid];
  int pos = incl - s;
#pragma unroll
  for (int j = 0; j < 4; ++j) {
    if (m0[j]) order[b * SS + pos++] = tid * 4 + j;
  }
  if (tid == 255) counts[b] = incl;
}

// ---------------- kernel 2: embedding-gather + input GEMM ----------------
// xg[d][t][b][gate] (bf16), computed as C^T via swapped MFMA operands.
#define BM 128
#define BN 128
#define BK 32
#define LSTR 56

__global__ __launch_bounds__(256, 2) void k_gemm(
    const int* __restrict__ inputs, const int* __restrict__ seqlen,
    const float* __restrict__ emb,
    const float* __restrict__ Wih_f, const float* __restrict__ Wih_b,
    const float* __restrict__ bih_f, const float* __restrict__ bih_b,
    const float* __restrict__ bhh_f, const float* __restrict__ bhh_b,
    unsigned short* __restrict__ xg) {
  __shared__ short As[BM * LSTR];
  __shared__ short Bs[BN * LSTR];
  __shared__ int tokL[BM];

  const int d = blockIdx.y;
  const int mt = blockIdx.x >> 3, nt = blockIdx.x & 7;
  const int Mbase = mt * BM, Nbase = nt * BN;
  const int tid = threadIdx.x;
  const float* Wih = d ? Wih_b : Wih_f;

  if (tid < BM) {
    const int m = Mbase + tid;
    const int t = m >> 5, b = m & 31;
    int tok;
    if (d == 0) {
      tok = inputs[b * SS + t];
    } else {
      const int L = seqlen[b];
      tok = (t < L) ? inputs[b * SS + (L - 1 - t)] : 0;
    }
    tokL[tid] = tok;
  }
  __syncthreads();

  const int wave = tid >> 6, lane = tid & 63, ln = lane & 15, q = lane >> 4;
  const int wm = wave & 1, wn = wave >> 1;

  float4v acc[4][4];   // [ni (gate tile)][mi (txb tile)]
#pragma unroll
  for (int ni = 0; ni < 4; ++ni)
#pragma unroll
    for (int mi = 0; mi < 4; ++mi) acc[ni][mi] = (float4v){0.f, 0.f, 0.f, 0.f};

  for (int kb = 0; kb < (EE / BK); ++kb) {
    const int k0 = kb * BK;
    if (kb) __syncthreads();
#pragma unroll
    for (int i = 0; i < 2; ++i) {
      const int c = tid + i * 256;
      const int row = c >> 2, sub = c & 3;
      const short8 av = pack8(emb + (size_t)tokL[row] * EE + k0 + sub * 8);
      *(short8*)(As + row * LSTR + sub * 8) = av;
      const short8 bv = pack8(Wih + (size_t)(Nbase + row) * EE + k0 + sub * 8);
      *(short8*)(Bs + row * LSTR + sub * 8) = bv;
    }
    __syncthreads();
    short8 af[4], bfr[4];
#pragma unroll
    for (int mi = 0; mi < 4; ++mi)
      af[mi] = *(const short8*)(As + (wm * 64 + mi * 16 + ln) * LSTR + q * 8);
#pragma unroll
    for (int ni = 0; ni < 4; ++ni)
      bfr[ni] = *(const short8*)(Bs + (wn * 64 + ni * 16 + ln) * LSTR + q * 8);
#pragma unroll
    for (int ni = 0; ni < 4; ++ni)
#pragma unroll
      for (int mi = 0; mi < 4; ++mi)
        acc[ni][mi] = MFMA(bfr[ni], af[mi], acc[ni][mi]);   // swapped operands
  }

  const float* bih = d ? bih_b : bih_f;
  const float* bhh = d ? bhh_b : bhh_f;
  float biasv[4][4];
#pragma unroll
  for (int ni = 0; ni < 4; ++ni)
#pragma unroll
    for (int r = 0; r < 4; ++r) {
      const int col = Nbase + wn * 64 + ni * 16 + q * 4 + r;
      biasv[ni][r] = bih[col] + bhh[col];
    }
#pragma unroll
  for (int ni = 0; ni < 4; ++ni) {
    const int gate0 = Nbase + wn * 64 + ni * 16 + q * 4;
#pragma unroll
    for (int mi = 0; mi < 4; ++mi) {
      const int m = Mbase + wm * 64 + mi * 16 + ln;
      const int t = m >> 5, b0 = m & 31;
      ushort4v pk;
#pragma unroll
      for (int r = 0; r < 4; ++r) pk[r] = f2b(acc[ni][mi][r] + biasv[ni][r]);
      *(ushort4v*)(xg + (((size_t)d * SS + t) * BB + b0) * G4 + gate0) = pk;
    }
  }
}

// ---------------- kernel 3: recurrence (sentinel dataflow + LDS own-slice) ----------------
// Root cause of r2's 5.1ms (vs r0 3.25ms): each wave's sentinel poll set
// included qwords written BY ITS OWN BLOCK, so every step every wave waited
// for its own store to round-trip the MALL (store drain + poll RT ~ +2RT on
// the critical path). Fix: own-block h parts are exchanged through LDS
// (4KB double buffer + one lgkmcnt-only barrier per step -- NOT
// __syncthreads, which drains vmcnt and would re-add the store-RT stall);
// the MALL poll covers only the 14 FOREIGN qwords (substitution of own
// qwords uses compile-time indices -> cndmask, no scratch). Foreign
// producers run in phase, so the first poll usually lands at visibility.
// Retries back off with s_sleep. Store stays fire-and-forget agent-scope
// (write-through to MALL); data itself is the flag (hbuf pre-poisoned
// 0x7f7f = bf16 3.4e38, unreachable since |h|<=1; 8B stores don't tear).
// Correct under any block->XCD placement (all cross-block traffic is MALL).
#define SENTQ 0x7f7f7f7f7f7f7f7full

__global__ __launch_bounds__(256, 1) void k_recur(
    const float* __restrict__ Whh_f, const float* __restrict__ Whh_b,
    const unsigned short* __restrict__ xg, unsigned short* __restrict__ hbuf) {
  __shared__ unsigned long long lbuf[2][BB][8];   // [t-parity][chain][local qword]

  const int beta = blockIdx.x;
  const int xcd = beta & 7, slot = beta >> 3;   // blockIdx%8 ~ XCD (perf heuristic only)
  if (xcd >= 2) return;
  const int d = xcd, k = slot;
  const float* Whh = d ? Whh_b : Whh_f;
  const int tid = threadIdx.x;
  const int lane = tid & 63, ln = lane & 15, q = lane >> 4;
  const int wave = tid >> 6;
  const int g = wave & 1, nw = wave >> 1;
  const int chain = nw * 16 + ln;               // this lane's batch chain (C col)
  const int ubase = k * 32 + g * 16 + q * 4;    // first of this lane's 4 units (C rows)
  const int lqw = g * 4 + q;                    // local qword this lane produces

  // loop-invariant weight fragments: A[m][kk], m=ln, kk=q*8+j
  short8 w[4][8];
#pragma unroll
  for (int G = 0; G < 4; ++G) {
    const int grow = G * 256 + k * 32 + g * 16 + ln;
#pragma unroll
    for (int kt = 0; kt < 8; ++kt)
      w[G][kt] = pack8(Whh + (size_t)grow * HH + kt * 32 + q * 8);
  }

  float c4[4] = {0.f, 0.f, 0.f, 0.f};
  unsigned short* hb = hbuf + (size_t)d * 1025 * BB * HH;
  const unsigned short* xgd = xg + (size_t)d * SS * BB * G4;

  // xg for t=0 (transposed layout: 4 gates x 4 units contiguous per lane)
  ushort4v xc4[4], xn4[4];
#pragma unroll
  for (int G = 0; G < 4; ++G)
    xc4[G] = *(const ushort4v*)(xgd + ((size_t)0 * BB + chain) * G4 + G * 256 + ubase);

  for (int t = 0; t < SS; ++t) {
    // xg prefetch for t+1 first: completes under the poll wait.
    if (t + 1 < SS) {
#pragma unroll
      for (int G = 0; G < 4; ++G)
        xn4[G] = *(const ushort4v*)(xgd + ((size_t)(t + 1) * BB + chain) * G4 +
                                    G * 256 + ubase);
    }

    unsigned long long qv[16];
    if (t > 0) {
      // own-slice qwords (row qwords 8k+2q, 8k+2q+1) come from LDS, written
      // by own block last iteration and ordered by the barrier below.
      const unsigned long long own0 = lbuf[t & 1][chain][2 * q];
      const unsigned long long own1 = lbuf[t & 1][chain][2 * q + 1];
      // sentinel-poll the foreign 14 qwords of h_t's row (poll == load).
      const unsigned long long* hq =
          (const unsigned long long*)(hb + ((size_t)t * BB + chain) * HH) + q * 2;
      for (;;) {
#pragma unroll
        for (int i = 0; i < 16; ++i)
          qv[i] = __hip_atomic_load(hq + (i >> 1) * 8 + (i & 1),
                                    __ATOMIC_RELAXED, __HIP_MEMORY_SCOPE_AGENT);
        // substitute own-slice entries (i compile-time, k uniform -> cndmask)
#pragma unroll
        for (int i = 0; i < 16; ++i)
          if ((i >> 1) == k) qv[i] = (i & 1) ? own1 : own0;
        bool bad = false;
#pragma unroll
        for (int i = 0; i < 16; ++i) bad |= (qv[i] == SENTQ);
        if (!bad) break;
        __builtin_amdgcn_s_sleep(1);
      }
    }

    float4v acc[4];
#pragma unroll
    for (int G = 0; G < 4; ++G) acc[G] = (float4v){0.f, 0.f, 0.f, 0.f};
    if (t > 0) {
#pragma unroll
      for (int kt = 0; kt < 8; ++kt) {
        union { unsigned long long u[2]; short8 s; } hh;
        hh.u[0] = qv[kt * 2]; hh.u[1] = qv[kt * 2 + 1];
#pragma unroll
        for (int G = 0; G < 4; ++G) acc[G] = MFMA(w[G][kt], hh.s, acc[G]);
      }
    }

    unsigned long long pv = 0ull;
#pragma unroll
    for (int r = 0; r < 4; ++r) {
      const float gi = acc[0][r] + b2f(xc4[0][r]);
      const float gf = acc[1][r] + b2f(xc4[1][r]);
      const float gg = acc[2][r] + b2f(xc4[2][r]);
      const float go = acc[3][r] + b2f(xc4[3][r]);
      const float cn = sigm(gf) * c4[r] + sigm(gi) * tanh_f(gg);
      c4[r] = cn;
      const float h = sigm(go) * tanh_f(cn);
      pv |= ((unsigned long long)f2b(h)) << (16 * r);
    }
    // publish h_{t+1} for FOREIGN blocks: fire-and-forget agent store (the
    // data is the flag); own block gets it through LDS below.
    __hip_atomic_store(
        (unsigned long long*)(hb + ((size_t)(t + 1) * BB + chain) * HH + ubase),
        pv, __ATOMIC_RELAXED, __HIP_MEMORY_SCOPE_AGENT);
    lbuf[(t + 1) & 1][chain][lqw] = pv;

    // lgkmcnt-only barrier: orders LDS writes for all waves WITHOUT draining
    // vmcnt (a plain __syncthreads would stall on the global store + prefetch
    // queue every step). sched_barrier pins ds ops on each side (rule #18).
    __builtin_amdgcn_sched_barrier(0);
    asm volatile("s_waitcnt lgkmcnt(0)" ::: "memory");
    __builtin_amdgcn_s_barrier();
    __builtin_amdgcn_sched_barrier(0);

#pragma unroll
    for (int G = 0; G < 4; ++G) xc4[G] = xn4[G];
  }
}

// ---------------- kernel 4: masked compaction gather -> out (fp32) ----------------
__global__ __launch_bounds__(256) void k_gather(
    const unsigned short* __restrict__ hbuf, const int* __restrict__ order,
    const int* __restrict__ counts, float* __restrict__ out) {
  const int bj = blockIdx.x;            // (b, j)
  const int b = bj >> 10, j = bj & 1023;
  const int tid = threadIdx.x;
  const int cnt = counts[b];
  float2v val = (float2v){0.f, 0.f};
  if (j < cnt) {
    const int half = tid >> 7;          // 0: forward, 1: backward
    const int e2 = (tid & 127) * 2;
    const int tsel = half ? order[b * SS + (cnt - 1 - j)] : order[b * SS + j];
    const unsigned short* src =
        hbuf + (((size_t)half * 1025 + (tsel + 1)) * BB + b) * HH + e2;
    const unsigned int u = *(const unsigned int*)src;
    val[0] = b2f((unsigned short)u);
    val[1] = b2f((unsigned short)(u >> 16));
  }
  *(float2v*)(out + (size_t)bj * 512 + tid * 2) = val;
}

// ---------------- host ----------------
extern "C" void kernel_launch(void* const* d_in, const int* in_sizes, int n_in,
                              void* d_out, int out_size, void* d_ws, size_t ws_size,
                              hipStream_t stream) {
  (void)in_sizes; (void)n_in; (void)out_size; (void)ws_size;
  const int* inputs = (const int*)d_in[0];
  const int* seqlen = (const int*)d_in[1];
  const int* fmask  = (const int*)d_in[2];
  const float* emb  = (const float*)d_in[5];
  const float* fWih = (const float*)d_in[6];
  const float* fWhh = (const float*)d_in[7];
  const float* fbih = (const float*)d_in[8];
  const float* fbhh = (const float*)d_in[9];
  const float* bWih = (const float*)d_in[10];
  const float* bWhh = (const float*)d_in[11];
  const float* bbih = (const float*)d_in[12];
  const float* bbhh = (const float*)d_in[13];
  float* out = (float*)d_out;

  char* ws = (char*)d_ws;
  int* counts = (int*)(ws + 12800);             // 32 ints
  int* order  = (int*)(ws + 16384);             // 32*1024 ints
  const size_t o_hbuf = (size_t)1 << 18;
  unsigned short* hbuf = (unsigned short*)(ws + o_hbuf);          // 2*1025*32*256 bf16
  const size_t hbuf_bytes = (size_t)2 * 1025 * BB * HH * 2;       // 33,587,200
  const size_t o_xg = o_hbuf + hbuf_bytes;
  unsigned short* xg = (unsigned short*)(ws + o_xg);              // 2*1024*32*1024 bf16

  // poison hbuf with the sentinel pattern (bf16 0x7f7f = 3.4e38, a value the
  // recurrence can never produce); slot 0 is never read (t=0 skips the GEMM).
  hipMemsetAsync(hbuf, 0x7f, hbuf_bytes, stream);

  k_scan<<<32, 256, 0, stream>>>(fmask, order, counts);
  k_gemm<<<dim3(2048, 2), 256, 0, stream>>>(inputs, seqlen, emb, fWih, bWih,
                                            fbih, bbih, fbhh, bbhh, xg);
  k_recur<<<64, 256, 0, stream>>>(fWhh, bWhh, xg, hbuf);
  k_gather<<<BB * SS, 256, 0, stream>>>(hbuf, order, counts, out);
}

// Round 4
// 2848.965 us; speedup vs baseline: 1.8721x; 1.2951x over previous
//
#include <hip/hip_runtime.h>

// ---------------- problem constants ----------------
#define VV 50000
#define EE 512
#define HH 256
#define BB 32
#define SS 1024
#define G4 1024   // 4*H

typedef __attribute__((ext_vector_type(8))) short short8;
typedef __attribute__((ext_vector_type(4))) float float4v;
typedef __attribute__((ext_vector_type(2))) float float2v;
typedef __attribute__((ext_vector_type(4))) unsigned short ushort4v;
typedef __attribute__((ext_vector_type(4))) unsigned int uint4v;

#define MFMA(a, b, c) __builtin_amdgcn_mfma_f32_16x16x32_bf16(a, b, c, 0, 0, 0)

__device__ __forceinline__ float b2f(unsigned short u) {
  union { unsigned int i; float f; } v; v.i = ((unsigned int)u) << 16; return v.f;
}
__device__ __forceinline__ unsigned short f2b(float f) {
  union { float f; unsigned int i; } v; v.f = f;
  unsigned int u = v.i;
  return (unsigned short)((u + 0x7fffu + ((u >> 16) & 1u)) >> 16);
}
// pack 8 consecutive fp32 (16B-aligned) -> short8 of bf16
__device__ __forceinline__ short8 pack8(const float* p) {
  float4v x0 = *(const float4v*)p;
  float4v x1 = *(const float4v*)(p + 4);
  short8 r;
  r[0] = (short)f2b(x0[0]); r[1] = (short)f2b(x0[1]);
  r[2] = (short)f2b(x0[2]); r[3] = (short)f2b(x0[3]);
  r[4] = (short)f2b(x1[0]); r[5] = (short)f2b(x1[1]);
  r[6] = (short)f2b(x1[2]); r[7] = (short)f2b(x1[3]);
  return r;
}
__device__ __forceinline__ float sigm(float x) {
  return __builtin_amdgcn_rcpf(1.0f + __expf(-x));
}
__device__ __forceinline__ float tanh_f(float x) {
  return 1.0f - 2.0f * __builtin_amdgcn_rcpf(__expf(2.0f * x) + 1.0f);
}

// ---------------- kernel 1: fmask scan -> order/counts ----------------
__global__ __launch_bounds__(256) void k_scan(const int* __restrict__ fmask,
                                              int* __restrict__ order,
                                              int* __restrict__ counts) {
  __shared__ int sh[256];
  const int b = blockIdx.x;
  const int tid = threadIdx.x;
  int m0[4];
  const int base = b * SS + tid * 4;
#pragma unroll
  for (int j = 0; j < 4; ++j) m0[j] = fmask[base + j];
  const int s = m0[0] + m0[1] + m0[2] + m0[3];
  sh[tid] = s;
  __syncthreads();
  for (int off = 1; off < 256; off <<= 1) {
    int v = 0;
    if (tid >= off) v = sh[tid - off];
    __syncthreads();
    sh[tid] += v;
    __syncthreads();
  }
  const int incl = sh[tid];
  int pos = incl - s;
#pragma unroll
  for (int j = 0; j < 4; ++j) {
    if (m0[j]) order[b * SS + pos++] = tid * 4 + j;
  }
  if (tid == 255) counts[b] = incl;
}

// ---------------- kernel 2: embedding-gather + input GEMM ----------------
// xg[d][t][b][gate] (bf16), computed as C^T via swapped MFMA operands.
#define BM 128
#define BN 128
#define BK 32
#define LSTR 56

__global__ __launch_bounds__(256, 2) void k_gemm(
    const int* __restrict__ inputs, const int* __restrict__ seqlen,
    const float* __restrict__ emb,
    const float* __restrict__ Wih_f, const float* __restrict__ Wih_b,
    const float* __restrict__ bih_f, const float* __restrict__ bih_b,
    const float* __restrict__ bhh_f, const float* __restrict__ bhh_b,
    unsigned short* __restrict__ xg) {
  __shared__ short As[BM * LSTR];
  __shared__ short Bs[BN * LSTR];
  __shared__ int tokL[BM];

  const int d = blockIdx.y;
  const int mt = blockIdx.x >> 3, nt = blockIdx.x & 7;
  const int Mbase = mt * BM, Nbase = nt * BN;
  const int tid = threadIdx.x;
  const float* Wih = d ? Wih_b : Wih_f;

  if (tid < BM) {
    const int m = Mbase + tid;
    const int t = m >> 5, b = m & 31;
    int tok;
    if (d == 0) {
      tok = inputs[b * SS + t];
    } else {
      const int L = seqlen[b];
      tok = (t < L) ? inputs[b * SS + (L - 1 - t)] : 0;
    }
    tokL[tid] = tok;
  }
  __syncthreads();

  const int wave = tid >> 6, lane = tid & 63, ln = lane & 15, q = lane >> 4;
  const int wm = wave & 1, wn = wave >> 1;

  float4v acc[4][4];   // [ni (gate tile)][mi (txb tile)]
#pragma unroll
  for (int ni = 0; ni < 4; ++ni)
#pragma unroll
    for (int mi = 0; mi < 4; ++mi) acc[ni][mi] = (float4v){0.f, 0.f, 0.f, 0.f};

  for (int kb = 0; kb < (EE / BK); ++kb) {
    const int k0 = kb * BK;
    if (kb) __syncthreads();
#pragma unroll
    for (int i = 0; i < 2; ++i) {
      const int c = tid + i * 256;
      const int row = c >> 2, sub = c & 3;
      const short8 av = pack8(emb + (size_t)tokL[row] * EE + k0 + sub * 8);
      *(short8*)(As + row * LSTR + sub * 8) = av;
      const short8 bv = pack8(Wih + (size_t)(Nbase + row) * EE + k0 + sub * 8);
      *(short8*)(Bs + row * LSTR + sub * 8) = bv;
    }
    __syncthreads();
    short8 af[4], bfr[4];
#pragma unroll
    for (int mi = 0; mi < 4; ++mi)
      af[mi] = *(const short8*)(As + (wm * 64 + mi * 16 + ln) * LSTR + q * 8);
#pragma unroll
    for (int ni = 0; ni < 4; ++ni)
      bfr[ni] = *(const short8*)(Bs + (wn * 64 + ni * 16 + ln) * LSTR + q * 8);
#pragma unroll
    for (int ni = 0; ni < 4; ++ni)
#pragma unroll
      for (int mi = 0; mi < 4; ++mi)
        acc[ni][mi] = MFMA(bfr[ni], af[mi], acc[ni][mi]);   // swapped operands
  }

  const float* bih = d ? bih_b : bih_f;
  const float* bhh = d ? bhh_b : bhh_f;
  float biasv[4][4];
#pragma unroll
  for (int ni = 0; ni < 4; ++ni)
#pragma unroll
    for (int r = 0; r < 4; ++r) {
      const int col = Nbase + wn * 64 + ni * 16 + q * 4 + r;
      biasv[ni][r] = bih[col] + bhh[col];
    }
#pragma unroll
  for (int ni = 0; ni < 4; ++ni) {
    const int gate0 = Nbase + wn * 64 + ni * 16 + q * 4;
#pragma unroll
    for (int mi = 0; mi < 4; ++mi) {
      const int m = Mbase + wm * 64 + mi * 16 + ln;
      const int t = m >> 5, b0 = m & 31;
      ushort4v pk;
#pragma unroll
      for (int r = 0; r < 4; ++r) pk[r] = f2b(acc[ni][mi][r] + biasv[ni][r]);
      *(ushort4v*)(xg + (((size_t)d * SS + t) * BB + b0) * G4 + gate0) = pk;
    }
  }
}

// ---------------- kernel 3: recurrence (probed L2 fast path + MALL fallback) ----------------
// Rounds 0-3 all pinned at ~7.7k cy/step: every h exchange round-trips the
// MALL. Here each direction's 8 blocks TEST (init-time coherence probe)
// whether they can see each other through one XCD's L2 (blockIdx%8 grouping
// puts them there if dispatch round-robins XCDs). If ALL 8 pass (MALL-vote
// consensus), the group runs the L2 loop: plain 8B stores (write-through
// L1 -> land dirty in the shared L2) + batched global_load_dwordx4 sc0 nt
// sentinel polls (L1-bypass; probe-verified to see the dirty lines). No
// barriers, no atomics, no LDS in the steady loop. If any block fails the
// probe, the group runs the verbatim round-3 MALL loop (correct under any
// placement). Sentinel: hbuf pre-poisoned 0x7f7f (bf16 3.4e38, unreachable
// since |h|<=1; 8B stores don't tear). t=0 skips the h-GEMM (h_0 = 0).
#define SENTQ 0x7f7f7f7f7f7f7f7full
#define PMAGIC 0x51A600

__device__ __forceinline__ int l2probe(const int* p) {
  int v;
  asm volatile("global_load_dword %0, %1, off sc0 nt\n\t"
               "s_waitcnt vmcnt(0)"
               : "=v"(v) : "v"(p) : "memory");
  return v;
}

__device__ __forceinline__ void l2row8(const void* p, uint4v* r) {
  asm volatile(
      "global_load_dwordx4 %0, %8, off sc0 nt\n\t"
      "global_load_dwordx4 %1, %8, off offset:64 sc0 nt\n\t"
      "global_load_dwordx4 %2, %8, off offset:128 sc0 nt\n\t"
      "global_load_dwordx4 %3, %8, off offset:192 sc0 nt\n\t"
      "global_load_dwordx4 %4, %8, off offset:256 sc0 nt\n\t"
      "global_load_dwordx4 %5, %8, off offset:320 sc0 nt\n\t"
      "global_load_dwordx4 %6, %8, off offset:384 sc0 nt\n\t"
      "global_load_dwordx4 %7, %8, off offset:448 sc0 nt\n\t"
      "s_waitcnt vmcnt(0)"
      : "=&v"(r[0]), "=&v"(r[1]), "=&v"(r[2]), "=&v"(r[3]),
        "=&v"(r[4]), "=&v"(r[5]), "=&v"(r[6]), "=&v"(r[7])
      : "v"(p)
      : "memory");
}

__global__ __launch_bounds__(256, 1) void k_recur(
    const float* __restrict__ Whh_f, const float* __restrict__ Whh_b,
    const unsigned short* __restrict__ xg, unsigned short* __restrict__ hbuf,
    int* __restrict__ proto) {
  __shared__ unsigned long long lbuf[2][BB][8];   // fallback own-slice exchange
  __shared__ int s_mode;

  const int beta = blockIdx.x;
  const int xcd = beta & 7, slot = beta >> 3;
  if (xcd >= 2) return;
  const int d = xcd, k = slot;
  const float* Whh = d ? Whh_b : Whh_f;
  const int tid = threadIdx.x;
  const int lane = tid & 63, ln = lane & 15, q = lane >> 4;
  const int wave = tid >> 6;
  const int g = wave & 1, nw = wave >> 1;
  const int chain = nw * 16 + ln;               // this lane's batch chain (C col)
  const int ubase = k * 32 + g * 16 + q * 4;    // first of this lane's 4 units (C rows)
  const int lqw = g * 4 + q;                    // local qword this lane produces

  // ---- init: coherence probe + per-group consensus vote ----
  // probes[d*8+r] at proto+0 (16 ints), vote_ok at proto+16, vote_n at proto+18.
  if (tid == 0) {
    int* probes = proto;
    int* vote_ok = proto + 16;
    int* vote_n = proto + 18;
    probes[d * 8 + k] = PMAGIC + k;   // plain store: same type as L2-mode h store
    int ok = 0;
    for (int it = 0; it < 256 && !ok; ++it) {
      ok = 1;
#pragma unroll
      for (int s = 0; s < 8; ++s)
        ok &= (l2probe(probes + d * 8 + s) == PMAGIC + s);
    }
    __hip_atomic_fetch_add(vote_ok + d, ok, __ATOMIC_RELAXED,
                           __HIP_MEMORY_SCOPE_AGENT);
    __hip_atomic_fetch_add(vote_n + d, 1, __ATOMIC_RELEASE,
                           __HIP_MEMORY_SCOPE_AGENT);
    while (__hip_atomic_load(vote_n + d, __ATOMIC_ACQUIRE,
                             __HIP_MEMORY_SCOPE_AGENT) < 8) {}
    s_mode = (__hip_atomic_load(vote_ok + d, __ATOMIC_RELAXED,
                                __HIP_MEMORY_SCOPE_AGENT) == 8);
  }
  __syncthreads();
  const int mode_l2 = s_mode;

  // loop-invariant weight fragments: A[m][kk], m=ln, kk=q*8+j
  short8 w[4][8];
#pragma unroll
  for (int G = 0; G < 4; ++G) {
    const int grow = G * 256 + k * 32 + g * 16 + ln;
#pragma unroll
    for (int kt = 0; kt < 8; ++kt)
      w[G][kt] = pack8(Whh + (size_t)grow * HH + kt * 32 + q * 8);
  }

  float c4[4] = {0.f, 0.f, 0.f, 0.f};
  unsigned short* hb = hbuf + (size_t)d * 1025 * BB * HH;
  const unsigned short* xgd = xg + (size_t)d * SS * BB * G4;

  // xg for t=0 (transposed layout: 4 gates x 4 units contiguous per lane)
  ushort4v xc4[4], xn4[4];
#pragma unroll
  for (int G = 0; G < 4; ++G)
    xc4[G] = *(const ushort4v*)(xgd + ((size_t)0 * BB + chain) * G4 + G * 256 + ubase);

  if (mode_l2) {
    // ---------- L2 fast path: plain stores + sc0/nt sentinel polls ----------
    for (int t = 0; t < SS; ++t) {
      if (t + 1 < SS) {
#pragma unroll
        for (int G = 0; G < 4; ++G)
          xn4[G] = *(const ushort4v*)(xgd + ((size_t)(t + 1) * BB + chain) * G4 +
                                      G * 256 + ubase);
      }

      float4v acc[4];
#pragma unroll
      for (int G = 0; G < 4; ++G) acc[G] = (float4v){0.f, 0.f, 0.f, 0.f};

      if (t > 0) {
        union Q16 { uint4v v; unsigned long long qq[2]; short8 s8; } rr[8];
        const char* hq =
            (const char*)(hb + ((size_t)t * BB + chain) * HH) + q * 16;
        for (;;) {
          uint4v tmp[8];
          l2row8(hq, tmp);
#pragma unroll
          for (int j = 0; j < 8; ++j) rr[j].v = tmp[j];
          bool bad = false;
#pragma unroll
          for (int j = 0; j < 8; ++j)
            bad |= (rr[j].qq[0] == SENTQ) | (rr[j].qq[1] == SENTQ);
          if (!bad) break;
        }
#pragma unroll
        for (int kt = 0; kt < 8; ++kt)
#pragma unroll
          for (int G = 0; G < 4; ++G) acc[G] = MFMA(w[G][kt], rr[kt].s8, acc[G]);
      }

      unsigned long long pv = 0ull;
#pragma unroll
      for (int r = 0; r < 4; ++r) {
        const float gi = acc[0][r] + b2f(xc4[0][r]);
        const float gf = acc[1][r] + b2f(xc4[1][r]);
        const float gg = acc[2][r] + b2f(xc4[2][r]);
        const float go = acc[3][r] + b2f(xc4[3][r]);
        const float cn = sigm(gf) * c4[r] + sigm(gi) * tanh_f(gg);
        c4[r] = cn;
        const float h = sigm(go) * tanh_f(cn);
        pv |= ((unsigned long long)f2b(h)) << (16 * r);
      }
      // plain store: write-through L1 -> dirty line in the group's shared L2;
      // the data itself is the flag.
      *(unsigned long long*)(hb + ((size_t)(t + 1) * BB + chain) * HH + ubase) = pv;

#pragma unroll
      for (int G = 0; G < 4; ++G) xc4[G] = xn4[G];
    }
  } else {
    // ---------- MALL fallback: verbatim round-3 loop ----------
    for (int t = 0; t < SS; ++t) {
      if (t + 1 < SS) {
#pragma unroll
        for (int G = 0; G < 4; ++G)
          xn4[G] = *(const ushort4v*)(xgd + ((size_t)(t + 1) * BB + chain) * G4 +
                                      G * 256 + ubase);
      }

      unsigned long long qv[16];
      if (t > 0) {
        const unsigned long long own0 = lbuf[t & 1][chain][2 * q];
        const unsigned long long own1 = lbuf[t & 1][chain][2 * q + 1];
        const unsigned long long* hq =
            (const unsigned long long*)(hb + ((size_t)t * BB + chain) * HH) + q * 2;
        for (;;) {
#pragma unroll
          for (int i = 0; i < 16; ++i)
            qv[i] = __hip_atomic_load(hq + (i >> 1) * 8 + (i & 1),
                                      __ATOMIC_RELAXED, __HIP_MEMORY_SCOPE_AGENT);
#pragma unroll
          for (int i = 0; i < 16; ++i)
            if ((i >> 1) == k) qv[i] = (i & 1) ? own1 : own0;
          bool bad = false;
#pragma unroll
          for (int i = 0; i < 16; ++i) bad |= (qv[i] == SENTQ);
          if (!bad) break;
          __builtin_amdgcn_s_sleep(1);
        }
      }

      float4v acc[4];
#pragma unroll
      for (int G = 0; G < 4; ++G) acc[G] = (float4v){0.f, 0.f, 0.f, 0.f};
      if (t > 0) {
#pragma unroll
        for (int kt = 0; kt < 8; ++kt) {
          union { unsigned long long u[2]; short8 s; } hh;
          hh.u[0] = qv[kt * 2]; hh.u[1] = qv[kt * 2 + 1];
#pragma unroll
          for (int G = 0; G < 4; ++G) acc[G] = MFMA(w[G][kt], hh.s, acc[G]);
        }
      }

      unsigned long long pv = 0ull;
#pragma unroll
      for (int r = 0; r < 4; ++r) {
        const float gi = acc[0][r] + b2f(xc4[0][r]);
        const float gf = acc[1][r] + b2f(xc4[1][r]);
        const float gg = acc[2][r] + b2f(xc4[2][r]);
        const float go = acc[3][r] + b2f(xc4[3][r]);
        const float cn = sigm(gf) * c4[r] + sigm(gi) * tanh_f(gg);
        c4[r] = cn;
        const float h = sigm(go) * tanh_f(cn);
        pv |= ((unsigned long long)f2b(h)) << (16 * r);
      }
      __hip_atomic_store(
          (unsigned long long*)(hb + ((size_t)(t + 1) * BB + chain) * HH + ubase),
          pv, __ATOMIC_RELAXED, __HIP_MEMORY_SCOPE_AGENT);
      lbuf[(t + 1) & 1][chain][lqw] = pv;

      __builtin_amdgcn_sched_barrier(0);
      asm volatile("s_waitcnt lgkmcnt(0)" ::: "memory");
      __builtin_amdgcn_s_barrier();
      __builtin_amdgcn_sched_barrier(0);

#pragma unroll
      for (int G = 0; G < 4; ++G) xc4[G] = xn4[G];
    }
  }
}

// ---------------- kernel 4: masked compaction gather -> out (fp32) ----------------
__global__ __launch_bounds__(256) void k_gather(
    const unsigned short* __restrict__ hbuf, const int* __restrict__ order,
    const int* __restrict__ counts, float* __restrict__ out) {
  const int bj = blockIdx.x;            // (b, j)
  const int b = bj >> 10, j = bj & 1023;
  const int tid = threadIdx.x;
  const int cnt = counts[b];
  float2v val = (float2v){0.f, 0.f};
  if (j < cnt) {
    const int half = tid >> 7;          // 0: forward, 1: backward
    const int e2 = (tid & 127) * 2;
    const int tsel = half ? order[b * SS + (cnt - 1 - j)] : order[b * SS + j];
    const unsigned short* src =
        hbuf + (((size_t)half * 1025 + (tsel + 1)) * BB + b) * HH + e2;
    const unsigned int u = *(const unsigned int*)src;
    val[0] = b2f((unsigned short)u);
    val[1] = b2f((unsigned short)(u >> 16));
  }
  *(float2v*)(out + (size_t)bj * 512 + tid * 2) = val;
}

// ---------------- host ----------------
extern "C" void kernel_launch(void* const* d_in, const int* in_sizes, int n_in,
                              void* d_out, int out_size, void* d_ws, size_t ws_size,
                              hipStream_t stream) {
  (void)in_sizes; (void)n_in; (void)out_size; (void)ws_size;
  const int* inputs = (const int*)d_in[0];
  const int* seqlen = (const int*)d_in[1];
  const int* fmask  = (const int*)d_in[2];
  const float* emb  = (const float*)d_in[5];
  const float* fWih = (const float*)d_in[6];
  const float* fWhh = (const float*)d_in[7];
  const float* fbih = (const float*)d_in[8];
  const float* fbhh = (const float*)d_in[9];
  const float* bWih = (const float*)d_in[10];
  const float* bWhh = (const float*)d_in[11];
  const float* bbih = (const float*)d_in[12];
  const float* bbhh = (const float*)d_in[13];
  float* out = (float*)d_out;

  char* ws = (char*)d_ws;
  int* proto  = (int*)(ws + 0);                 // 16 probes + 2 vote_ok + 2 vote_n
  int* counts = (int*)(ws + 12800);             // 32 ints
  int* order  = (int*)(ws + 16384);             // 32*1024 ints
  const size_t o_hbuf = (size_t)1 << 18;
  unsigned short* hbuf = (unsigned short*)(ws + o_hbuf);          // 2*1025*32*256 bf16
  const size_t hbuf_bytes = (size_t)2 * 1025 * BB * HH * 2;       // 33,587,200
  const size_t o_xg = o_hbuf + hbuf_bytes;
  unsigned short* xg = (unsigned short*)(ws + o_xg);              // 2*1024*32*1024 bf16

  hipMemsetAsync(proto, 0, 128, stream);
  // poison hbuf with the sentinel pattern (bf16 0x7f7f = 3.4e38, a value the
  // recurrence can never produce); slot 0 is never read (t=0 skips the GEMM).
  hipMemsetAsync(hbuf, 0x7f, hbuf_bytes, stream);

  k_scan<<<32, 256, 0, stream>>>(fmask, order, counts);
  k_gemm<<<dim3(2048, 2), 256, 0, stream>>>(inputs, seqlen, emb, fWih, bWih,
                                            fbih, bbih, fbhh, bbhh, xg);
  k_recur<<<64, 256, 0, stream>>>(fWhh, bWhh, xg, hbuf, proto);
  k_gather<<<BB * SS, 256, 0, stream>>>(hbuf, order, counts, out);
}

// Round 6
// 2760.748 us; speedup vs baseline: 1.9319x; 1.0320x over previous
//
#include <hip/hip_runtime.h>

// ---------------- problem constants ----------------
#define VV 50000
#define EE 512
#define HH 256
#define BB 32
#define SS 1024
#define G4 1024   // 4*H

typedef __attribute__((ext_vector_type(8))) short short8;
typedef __attribute__((ext_vector_type(4))) float float4v;
typedef __attribute__((ext_vector_type(2))) float float2v;
typedef __attribute__((ext_vector_type(4))) unsigned short ushort4v;
typedef __attribute__((ext_vector_type(4))) unsigned int uint4v;

#define MFMA(a, b, c) __builtin_amdgcn_mfma_f32_16x16x32_bf16(a, b, c, 0, 0, 0)

__device__ __forceinline__ float b2f(unsigned short u) {
  union { unsigned int i; float f; } v; v.i = ((unsigned int)u) << 16; return v.f;
}
__device__ __forceinline__ unsigned short f2b(float f) {
  union { float f; unsigned int i; } v; v.f = f;
  unsigned int u = v.i;
  return (unsigned short)((u + 0x7fffu + ((u >> 16) & 1u)) >> 16);
}
// pack 8 consecutive fp32 (16B-aligned) -> short8 of bf16
__device__ __forceinline__ short8 pack8(const float* p) {
  float4v x0 = *(const float4v*)p;
  float4v x1 = *(const float4v*)(p + 4);
  short8 r;
  r[0] = (short)f2b(x0[0]); r[1] = (short)f2b(x0[1]);
  r[2] = (short)f2b(x0[2]); r[3] = (short)f2b(x0[3]);
  r[4] = (short)f2b(x1[0]); r[5] = (short)f2b(x1[1]);
  r[6] = (short)f2b(x1[2]); r[7] = (short)f2b(x1[3]);
  return r;
}
__device__ __forceinline__ float sigm(float x) {
  return __builtin_amdgcn_rcpf(1.0f + __expf(-x));
}
__device__ __forceinline__ float tanh_f(float x) {
  return 1.0f - 2.0f * __builtin_amdgcn_rcpf(__expf(2.0f * x) + 1.0f);
}

// ---------------- kernel 1: fmask scan -> order/counts ----------------
__global__ __launch_bounds__(256) void k_scan(const int* __restrict__ fmask,
                                              int* __restrict__ order,
                                              int* __restrict__ counts) {
  __shared__ int sh[256];
  const int b = blockIdx.x;
  const int tid = threadIdx.x;
  int m0[4];
  const int base = b * SS + tid * 4;
#pragma unroll
  for (int j = 0; j < 4; ++j) m0[j] = fmask[base + j];
  const int s = m0[0] + m0[1] + m0[2] + m0[3];
  sh[tid] = s;
  __syncthreads();
  for (int off = 1; off < 256; off <<= 1) {
    int v = 0;
    if (tid >= off) v = sh[tid - off];
    __syncthreads();
    sh[tid] += v;
    __syncthreads();
  }
  const int incl = sh[tid];
  int pos = incl - s;
#pragma unroll
  for (int j = 0; j < 4; ++j) {
    if (m0[j]) order[b * SS + pos++] = tid * 4 + j;
  }
  if (tid == 255) counts[b] = incl;
}

// ---------------- kernel 2: embedding-gather + input GEMM ----------------
// xg[d][t][b][gate] (bf16), computed as C^T via swapped MFMA operands.
#define BM 128
#define BN 128
#define BK 32
#define LSTR 56

__global__ __launch_bounds__(256, 2) void k_gemm(
    const int* __restrict__ inputs, const int* __restrict__ seqlen,
    const float* __restrict__ emb,
    const float* __restrict__ Wih_f, const float* __restrict__ Wih_b,
    const float* __restrict__ bih_f, const float* __restrict__ bih_b,
    const float* __restrict__ bhh_f, const float* __restrict__ bhh_b,
    unsigned short* __restrict__ xg) {
  __shared__ short As[BM * LSTR];
  __shared__ short Bs[BN * LSTR];
  __shared__ int tokL[BM];

  const int d = blockIdx.y;
  const int mt = blockIdx.x >> 3, nt = blockIdx.x & 7;
  const int Mbase = mt * BM, Nbase = nt * BN;
  const int tid = threadIdx.x;
  const float* Wih = d ? Wih_b : Wih_f;

  if (tid < BM) {
    const int m = Mbase + tid;
    const int t = m >> 5, b = m & 31;
    int tok;
    if (d == 0) {
      tok = inputs[b * SS + t];
    } else {
      const int L = seqlen[b];
      tok = (t < L) ? inputs[b * SS + (L - 1 - t)] : 0;
    }
    tokL[tid] = tok;
  }
  __syncthreads();

  const int wave = tid >> 6, lane = tid & 63, ln = lane & 15, q = lane >> 4;
  const int wm = wave & 1, wn = wave >> 1;

  float4v acc[4][4];   // [ni (gate tile)][mi (txb tile)]
#pragma unroll
  for (int ni = 0; ni < 4; ++ni)
#pragma unroll
    for (int mi = 0; mi < 4; ++mi) acc[ni][mi] = (float4v){0.f, 0.f, 0.f, 0.f};

  for (int kb = 0; kb < (EE / BK); ++kb) {
    const int k0 = kb * BK;
    if (kb) __syncthreads();
#pragma unroll
    for (int i = 0; i < 2; ++i) {
      const int c = tid + i * 256;
      const int row = c >> 2, sub = c & 3;
      const short8 av = pack8(emb + (size_t)tokL[row] * EE + k0 + sub * 8);
      *(short8*)(As + row * LSTR + sub * 8) = av;
      const short8 bv = pack8(Wih + (size_t)(Nbase + row) * EE + k0 + sub * 8);
      *(short8*)(Bs + row * LSTR + sub * 8) = bv;
    }
    __syncthreads();
    short8 af[4], bfr[4];
#pragma unroll
    for (int mi = 0; mi < 4; ++mi)
      af[mi] = *(const short8*)(As + (wm * 64 + mi * 16 + ln) * LSTR + q * 8);
#pragma unroll
    for (int ni = 0; ni < 4; ++ni)
      bfr[ni] = *(const short8*)(Bs + (wn * 64 + ni * 16 + ln) * LSTR + q * 8);
#pragma unroll
    for (int ni = 0; ni < 4; ++ni)
#pragma unroll
      for (int mi = 0; mi < 4; ++mi)
        acc[ni][mi] = MFMA(bfr[ni], af[mi], acc[ni][mi]);   // swapped operands
  }

  const float* bih = d ? bih_b : bih_f;
  const float* bhh = d ? bhh_b : bhh_f;
  float biasv[4][4];
#pragma unroll
  for (int ni = 0; ni < 4; ++ni)
#pragma unroll
    for (int r = 0; r < 4; ++r) {
      const int col = Nbase + wn * 64 + ni * 16 + q * 4 + r;
      biasv[ni][r] = bih[col] + bhh[col];
    }
#pragma unroll
  for (int ni = 0; ni < 4; ++ni) {
    const int gate0 = Nbase + wn * 64 + ni * 16 + q * 4;
#pragma unroll
    for (int mi = 0; mi < 4; ++mi) {
      const int m = Mbase + wm * 64 + mi * 16 + ln;
      const int t = m >> 5, b0 = m & 31;
      ushort4v pk;
#pragma unroll
      for (int r = 0; r < 4; ++r) pk[r] = f2b(acc[ni][mi][r] + biasv[ni][r]);
      *(ushort4v*)(xg + (((size_t)d * SS + t) * BB + b0) * G4 + gate0) = pk;
    }
  }
}

// ---------------- kernel 3: recurrence (probed L2 fast path + MALL fallback) ----------------
// LESSON (r1/r5 both hung, r4 passed): on gfx950 the poll loads MUST carry
// 'sc0 nt'. 'nt' (evict-first) is the correctness-carrying flag here: a
// consumer re-polls the SAME line; without nt the line parks in L1 and every
// retry hits the stale sentinel copy forever (first touch is an L1 miss, so
// the init-time probe still passes -> steady-loop hang). Do NOT remove nt.
//
// r4 post-mortem (2496us, L2 mode proven engaged): remaining per-step cost
// included a self-inflicted drain: the xg prefetch (HBM, ~900cy) was issued
// immediately before the poll, whose s_waitcnt vmcnt(0) waits oldest-first.
// This round keeps r4's substrate verbatim and only restructures xg into
// 4-step groups: the next group's 16 loads are issued right AFTER a poll
// detect (natural vmcnt==0 point), so polls stop draining fresh HBM loads.
//
// Substrate (r4-proven): plain 8B h stores (write-through L1 -> dirty line
// in the group's shared L2) + batched dwordx4 'sc0 nt' sentinel polls; an
// init-time coherence probe + MALL-vote engages L2 mode only if all 8
// blocks of a direction see each other through L2; otherwise the verbatim
// r3 MALL loop runs (correct under any placement). Sentinel: hbuf
// pre-poisoned 0x7f7f (bf16 3.4e38, unreachable since |h|<=1; 8B stores
// don't tear). t=0 skips the h-GEMM (h_0 = 0).
#define SENTQ 0x7f7f7f7f7f7f7f7full
#define PMAGIC 0x51A600

__device__ __forceinline__ int l2probe(const int* p) {
  int v;
  asm volatile("global_load_dword %0, %1, off sc0 nt\n\t"
               "s_waitcnt vmcnt(0)"
               : "=v"(v) : "v"(p) : "memory");
  return v;
}

__device__ __forceinline__ void l2row8(const void* p, uint4v* r) {
  asm volatile(
      "global_load_dwordx4 %0, %8, off sc0 nt\n\t"
      "global_load_dwordx4 %1, %8, off offset:64 sc0 nt\n\t"
      "global_load_dwordx4 %2, %8, off offset:128 sc0 nt\n\t"
      "global_load_dwordx4 %3, %8, off offset:192 sc0 nt\n\t"
      "global_load_dwordx4 %4, %8, off offset:256 sc0 nt\n\t"
      "global_load_dwordx4 %5, %8, off offset:320 sc0 nt\n\t"
      "global_load_dwordx4 %6, %8, off offset:384 sc0 nt\n\t"
      "global_load_dwordx4 %7, %8, off offset:448 sc0 nt\n\t"
      "s_waitcnt vmcnt(0)"
      : "=&v"(r[0]), "=&v"(r[1]), "=&v"(r[2]), "=&v"(r[3]),
        "=&v"(r[4]), "=&v"(r[5]), "=&v"(r[6]), "=&v"(r[7])
      : "v"(p)
      : "memory");
}

__global__ __launch_bounds__(256, 1) void k_recur(
    const float* __restrict__ Whh_f, const float* __restrict__ Whh_b,
    const unsigned short* __restrict__ xg, unsigned short* __restrict__ hbuf,
    int* __restrict__ proto) {
  __shared__ unsigned long long lbuf[2][BB][8];   // fallback own-slice exchange
  __shared__ int s_mode;

  const int beta = blockIdx.x;
  const int xcd = beta & 7, slot = beta >> 3;
  if (xcd >= 2) return;
  const int d = xcd, k = slot;
  const float* Whh = d ? Whh_b : Whh_f;
  const int tid = threadIdx.x;
  const int lane = tid & 63, ln = lane & 15, q = lane >> 4;
  const int wave = tid >> 6;
  const int g = wave & 1, nw = wave >> 1;
  const int chain = nw * 16 + ln;               // this lane's batch chain (C col)
  const int ubase = k * 32 + g * 16 + q * 4;    // first of this lane's 4 units (C rows)
  const int lqw = g * 4 + q;                    // local qword this lane produces

  // ---- init: coherence probe + per-group consensus vote ----
  // probes[d*8+r] at proto+0 (16 ints), vote_ok at proto+16, vote_n at proto+18.
  if (tid == 0) {
    int* probes = proto;
    int* vote_ok = proto + 16;
    int* vote_n = proto + 18;
    probes[d * 8 + k] = PMAGIC + k;   // plain store: same type as L2-mode h store
    int ok = 0;
    for (int it = 0; it < 256 && !ok; ++it) {
      ok = 1;
#pragma unroll
      for (int s = 0; s < 8; ++s)
        ok &= (l2probe(probes + d * 8 + s) == PMAGIC + s);
    }
    __hip_atomic_fetch_add(vote_ok + d, ok, __ATOMIC_RELAXED,
                           __HIP_MEMORY_SCOPE_AGENT);
    __hip_atomic_fetch_add(vote_n + d, 1, __ATOMIC_RELEASE,
                           __HIP_MEMORY_SCOPE_AGENT);
    while (__hip_atomic_load(vote_n + d, __ATOMIC_ACQUIRE,
                             __HIP_MEMORY_SCOPE_AGENT) < 8) {}
    s_mode = (__hip_atomic_load(vote_ok + d, __ATOMIC_RELAXED,
                                __HIP_MEMORY_SCOPE_AGENT) == 8);
  }
  __syncthreads();
  const int mode_l2 = s_mode;

  // loop-invariant weight fragments: A[m][kk], m=ln, kk=q*8+j
  short8 w[4][8];
#pragma unroll
  for (int G = 0; G < 4; ++G) {
    const int grow = G * 256 + k * 32 + g * 16 + ln;
#pragma unroll
    for (int kt = 0; kt < 8; ++kt)
      w[G][kt] = pack8(Whh + (size_t)grow * HH + kt * 32 + q * 8);
  }

  float c4[4] = {0.f, 0.f, 0.f, 0.f};
  unsigned short* hb = hbuf + (size_t)d * 1025 * BB * HH;
  const unsigned short* xgd = xg + (size_t)d * SS * BB * G4;

  if (mode_l2) {
    // ---------- L2 fast path: plain stores + sc0 nt sentinel polls ----------
    // xg handled in 4-step groups: xc = current group's gate inputs,
    // xn = next group's, issued right after a poll detect (vmcnt==0 point).
    ushort4v xc[4][4], xn[4][4];   // [s in group][G]
#pragma unroll
    for (int s = 0; s < 4; ++s)
#pragma unroll
      for (int G = 0; G < 4; ++G)
        xc[s][G] = *(const ushort4v*)(xgd + ((size_t)s * BB + chain) * G4 +
                                      G * 256 + ubase);

    for (int t0 = 0; t0 < SS; t0 += 4) {
#pragma unroll
      for (int s = 0; s < 4; ++s) {
        const int t = t0 + s;
        const bool have = (s > 0) || (t0 > 0);   // t==0 has no h input

        union Q16 { uint4v v; unsigned long long qq[2]; short8 s8; } rr[8];
        if (have) {
          const char* hq =
              (const char*)(hb + ((size_t)t * BB + chain) * HH) + q * 16;
          for (;;) {
            uint4v tmp[8];
            l2row8(hq, tmp);
#pragma unroll
            for (int j = 0; j < 8; ++j) rr[j].v = tmp[j];
            bool bad = false;
#pragma unroll
            for (int j = 0; j < 8; ++j)
              bad |= (rr[j].qq[0] == SENTQ) | (rr[j].qq[1] == SENTQ);
            if (!bad) break;
          }
        }

        // issue next group's xg loads ONCE per group, right after a detect:
        // vmcnt is 0 here, and the next poll is a full step away, so these
        // never serialize inside a poll wait again.
        if (s == 0 && t0 + 4 < SS) {
#pragma unroll
          for (int s2 = 0; s2 < 4; ++s2)
#pragma unroll
            for (int G = 0; G < 4; ++G)
              xn[s2][G] = *(const ushort4v*)(xgd +
                                             ((size_t)(t0 + 4 + s2) * BB + chain) * G4 +
                                             G * 256 + ubase);
        }

        float4v acc[4];
#pragma unroll
        for (int G = 0; G < 4; ++G) acc[G] = (float4v){0.f, 0.f, 0.f, 0.f};
        if (have) {
#pragma unroll
          for (int kt = 0; kt < 8; ++kt)
#pragma unroll
            for (int G = 0; G < 4; ++G) acc[G] = MFMA(w[G][kt], rr[kt].s8, acc[G]);
        }

        unsigned long long pv = 0ull;
#pragma unroll
        for (int r = 0; r < 4; ++r) {
          const float gi = acc[0][r] + b2f(xc[s][0][r]);
          const float gf = acc[1][r] + b2f(xc[s][1][r]);
          const float gg = acc[2][r] + b2f(xc[s][2][r]);
          const float go = acc[3][r] + b2f(xc[s][3][r]);
          const float cn = sigm(gf) * c4[r] + sigm(gi) * tanh_f(gg);
          c4[r] = cn;
          const float h = sigm(go) * tanh_f(cn);
          pv |= ((unsigned long long)f2b(h)) << (16 * r);
        }
        // plain store: write-through L1 -> dirty line in the group's shared
        // L2; the data itself is the flag.
        *(unsigned long long*)(hb + ((size_t)(t + 1) * BB + chain) * HH + ubase) = pv;
      }
      if (t0 + 4 < SS) {
#pragma unroll
        for (int s = 0; s < 4; ++s)
#pragma unroll
          for (int G = 0; G < 4; ++G) xc[s][G] = xn[s][G];
      }
    }
  } else {
    // ---------- MALL fallback: verbatim round-3 loop ----------
    ushort4v xc4[4], xn4[4];
#pragma unroll
    for (int G = 0; G < 4; ++G)
      xc4[G] = *(const ushort4v*)(xgd + ((size_t)0 * BB + chain) * G4 +
                                  G * 256 + ubase);
    for (int t = 0; t < SS; ++t) {
      if (t + 1 < SS) {
#pragma unroll
        for (int G = 0; G < 4; ++G)
          xn4[G] = *(const ushort4v*)(xgd + ((size_t)(t + 1) * BB + chain) * G4 +
                                      G * 256 + ubase);
      }

      unsigned long long qv[16];
      if (t > 0) {
        const unsigned long long own0 = lbuf[t & 1][chain][2 * q];
        const unsigned long long own1 = lbuf[t & 1][chain][2 * q + 1];
        const unsigned long long* hq =
            (const unsigned long long*)(hb + ((size_t)t * BB + chain) * HH) + q * 2;
        for (;;) {
#pragma unroll
          for (int i = 0; i < 16; ++i)
            qv[i] = __hip_atomic_load(hq + (i >> 1) * 8 + (i & 1),
                                      __ATOMIC_RELAXED, __HIP_MEMORY_SCOPE_AGENT);
#pragma unroll
          for (int i = 0; i < 16; ++i)
            if ((i >> 1) == k) qv[i] = (i & 1) ? own1 : own0;
          bool bad = false;
#pragma unroll
          for (int i = 0; i < 16; ++i) bad |= (qv[i] == SENTQ);
          if (!bad) break;
          __builtin_amdgcn_s_sleep(1);
        }
      }

      float4v acc[4];
#pragma unroll
      for (int G = 0; G < 4; ++G) acc[G] = (float4v){0.f, 0.f, 0.f, 0.f};
      if (t > 0) {
#pragma unroll
        for (int kt = 0; kt < 8; ++kt) {
          union { unsigned long long u[2]; short8 s; } hh;
          hh.u[0] = qv[kt * 2]; hh.u[1] = qv[kt * 2 + 1];
#pragma unroll
          for (int G = 0; G < 4; ++G) acc[G] = MFMA(w[G][kt], hh.s, acc[G]);
        }
      }

      unsigned long long pv = 0ull;
#pragma unroll
      for (int r = 0; r < 4; ++r) {
        const float gi = acc[0][r] + b2f(xc4[0][r]);
        const float gf = acc[1][r] + b2f(xc4[1][r]);
        const float gg = acc[2][r] + b2f(xc4[2][r]);
        const float go = acc[3][r] + b2f(xc4[3][r]);
        const float cn = sigm(gf) * c4[r] + sigm(gi) * tanh_f(gg);
        c4[r] = cn;
        const float h = sigm(go) * tanh_f(cn);
        pv |= ((unsigned long long)f2b(h)) << (16 * r);
      }
      __hip_atomic_store(
          (unsigned long long*)(hb + ((size_t)(t + 1) * BB + chain) * HH + ubase),
          pv, __ATOMIC_RELAXED, __HIP_MEMORY_SCOPE_AGENT);
      lbuf[(t + 1) & 1][chain][lqw] = pv;

      __builtin_amdgcn_sched_barrier(0);
      asm volatile("s_waitcnt lgkmcnt(0)" ::: "memory");
      __builtin_amdgcn_s_barrier();
      __builtin_amdgcn_sched_barrier(0);

#pragma unroll
      for (int G = 0; G < 4; ++G) xc4[G] = xn4[G];
    }
  }
}

// ---------------- kernel 4: masked compaction gather -> out (fp32) ----------------
__global__ __launch_bounds__(256) void k_gather(
    const unsigned short* __restrict__ hbuf, const int* __restrict__ order,
    const int* __restrict__ counts, float* __restrict__ out) {
  const int bj = blockIdx.x;            // (b, j)
  const int b = bj >> 10, j = bj & 1023;
  const int tid = threadIdx.x;
  const int cnt = counts[b];
  float2v val = (float2v){0.f, 0.f};
  if (j < cnt) {
    const int half = tid >> 7;          // 0: forward, 1: backward
    const int e2 = (tid & 127) * 2;
    const int tsel = half ? order[b * SS + (cnt - 1 - j)] : order[b * SS + j];
    const unsigned short* src =
        hbuf + (((size_t)half * 1025 + (tsel + 1)) * BB + b) * HH + e2;
    const unsigned int u = *(const unsigned int*)src;
    val[0] = b2f((unsigned short)u);
    val[1] = b2f((unsigned short)(u >> 16));
  }
  *(float2v*)(out + (size_t)bj * 512 + tid * 2) = val;
}

// ---------------- host ----------------
extern "C" void kernel_launch(void* const* d_in, const int* in_sizes, int n_in,
                              void* d_out, int out_size, void* d_ws, size_t ws_size,
                              hipStream_t stream) {
  (void)in_sizes; (void)n_in; (void)out_size; (void)ws_size;
  const int* inputs = (const int*)d_in[0];
  const int* seqlen = (const int*)d_in[1];
  const int* fmask  = (const int*)d_in[2];
  const float* emb  = (const float*)d_in[5];
  const float* fWih = (const float*)d_in[6];
  const float* fWhh = (const float*)d_in[7];
  const float* fbih = (const float*)d_in[8];
  const float* fbhh = (const float*)d_in[9];
  const float* bWih = (const float*)d_in[10];
  const float* bWhh = (const float*)d_in[11];
  const float* bbih = (const float*)d_in[12];
  const float* bbhh = (const float*)d_in[13];
  float* out = (float*)d_out;

  char* ws = (char*)d_ws;
  int* proto  = (int*)(ws + 0);                 // 16 probes + 2 vote_ok + 2 vote_n
  int* counts = (int*)(ws + 12800);             // 32 ints
  int* order  = (int*)(ws + 16384);             // 32*1024 ints
  const size_t o_hbuf = (size_t)1 << 18;
  unsigned short* hbuf = (unsigned short*)(ws + o_hbuf);          // 2*1025*32*256 bf16
  const size_t hbuf_bytes = (size_t)2 * 1025 * BB * HH * 2;       // 33,587,200
  const size_t o_xg = o_hbuf + hbuf_bytes;
  unsigned short* xg = (unsigned short*)(ws + o_xg);              // 2*1024*32*1024 bf16

  hipMemsetAsync(proto, 0, 128, stream);
  // poison hbuf with the sentinel pattern (bf16 0x7f7f = 3.4e38, a value the
  // recurrence can never produce); slot 0 is never read (t=0 skips the GEMM).
  hipMemsetAsync(hbuf, 0x7f, hbuf_bytes, stream);

  k_scan<<<32, 256, 0, stream>>>(fmask, order, counts);
  k_gemm<<<dim3(2048, 2), 256, 0, stream>>>(inputs, seqlen, emb, fWih, bWih,
                                            fbih, bbih, fbhh, bbhh, xg);
  k_recur<<<64, 256, 0, stream>>>(fWhh, bWhh, xg, hbuf, proto);
  k_gather<<<BB * SS, 256, 0, stream>>>(hbuf, order, counts, out);
}